// Round 2
// baseline (373.692 us; speedup 1.0000x reference)
//
#include <hip/hip_runtime.h>

typedef int   i32x8 __attribute__((ext_vector_type(8)));
typedef float f32x4 __attribute__((ext_vector_type(4)));

#define B_   8
#define N_   4096
#define D_   256

// fp8 fragment-major blob layout:
//   blob[g16][kt][h] = 1 KB chunk; lane l's 16 bytes at +l*16 hold
//   P[g16*16 + (l&15)][k = kt*128 + (l>>4)*32 + h*16 .. +16]  (e4m3)

__device__ __forceinline__ void gl_lds16(const void* g, void* l) {
  __builtin_amdgcn_global_load_lds(
      (const __attribute__((address_space(1))) unsigned int*)g,
      (__attribute__((address_space(3))) unsigned int*)l, 16, 0, 0);
}

// sum of squares of the 4 e4m3 bytes in w (selector must be a literal)
__device__ __forceinline__ float sq8(unsigned w) {
  float f0 = __builtin_amdgcn_cvt_f32_fp8(w, 0);
  float f1 = __builtin_amdgcn_cvt_f32_fp8(w, 1);
  float f2 = __builtin_amdgcn_cvt_f32_fp8(w, 2);
  float f3 = __builtin_amdgcn_cvt_f32_fp8(w, 3);
  return f0 * f0 + f1 * f1 + f2 * f2 + f3 * f3;
}

// One wave per 16-row group: fp32 -> fp8 e4m3 convert (coalesced 1 KB float4
// reads), in-wave LDS transpose to fragment-major, norms of DEQUANTIZED
// values accumulated during readback, min-init.
__global__ __launch_bounds__(256) void prep_kernel(
    const float* __restrict__ x, const float* __restrict__ y,
    unsigned char* __restrict__ Xf, unsigned char* __restrict__ Yf,
    float* __restrict__ xx, float* __restrict__ yy,
    unsigned* __restrict__ rowmin, unsigned* __restrict__ colmin,
    float* __restrict__ out)
{
  __shared__ unsigned char T[4][16 * 272];   // 16 rows x 256B fp8 (+16 pad)
  if (blockIdx.x == 0 && threadIdx.x == 0) out[0] = 0.f;

  const int wv = threadIdx.x >> 6, lane = threadIdx.x & 63;
  const int wid = (blockIdx.x << 2) + wv;          // 0..4095

  const float* src; unsigned char* dst; float* nrm; unsigned* mn; int g;
  if (wid < 2048) { g = wid;        src = x; dst = Xf; nrm = xx; mn = rowmin; }
  else            { g = wid - 2048; src = y; dst = Yf; nrm = yy; mn = colmin; }

  unsigned char* tw = T[wv];
  const float* rp = src + (size_t)g * 16 * D_;
#pragma unroll
  for (int r = 0; r < 16; ++r) {
    float4 v = *(const float4*)(rp + r * D_ + lane * 4);   // 1 KB contiguous
    unsigned u = __builtin_amdgcn_cvt_pk_fp8_f32(v.x, v.y, 0, 0);
    u = __builtin_amdgcn_cvt_pk_fp8_f32(v.z, v.w, u, 1);   // bytes = x,y,z,w
    *(unsigned*)(tw + r * 272 + lane * 4) = u;
  }
  // Each wave only reads its own T[wv] slice; all cross-lane traffic is
  // intra-wave, so a wave-local lgkmcnt drain replaces the 4-wave rendezvous.
  asm volatile("s_waitcnt lgkmcnt(0)" ::: "memory");
  __builtin_amdgcn_wave_barrier();

  // fragment-order readback: row = lane&15, k-base = (lane>>4)*32
  float s = 0.f;
  const int row = lane & 15, ko = (lane >> 4) * 32;
#pragma unroll
  for (int kt = 0; kt < 2; ++kt)
#pragma unroll
    for (int h = 0; h < 2; ++h) {
      uint4 c = *(const uint4*)(tw + row * 272 + kt * 128 + ko + h * 16);
      s += sq8(c.x) + sq8(c.y) + sq8(c.z) + sq8(c.w);
      *(uint4*)(dst + ((((size_t)g * 2 + kt) * 2 + h) << 10) + lane * 16) = c;
    }
  s += __shfl_xor(s, 16, 64);   // fold quads: row (lane&15)'s full norm
  s += __shfl_xor(s, 32, 64);
  if      (lane < 16) nrm[g * 16 + lane] = s;
  else if (lane < 32) mn[g * 16 + lane - 16] = 0x7f800000u;   // +inf
}

// MX-fp8 chamfer GEMM (mfma_scale_f32_16x16x128_f8f6f4, scales = 1.0).
// Round-12: occupancy doubling. Grid was 1024 = 4 blocks/CU = 4 waves/SIMD
// (grid-limited); MfmaUtil 29% / VALUBusy 41% / HBM 4% = latency-bound.
// Block now 128 rows x 512 cols (8 col-eighths), ct tile = 16 cols = one
// contiguous 4 KB g16 blob (staging = identity 4 KB copy, 1 gl_lds16/thread).
// LDS 36.9 -> 18.4 KB, launch_bounds(256,8): 8 blocks/CU = 32 waves/CU.
__global__ __launch_bounds__(256, 8) void chamfer_gemm(
    const unsigned char* __restrict__ Xf, const unsigned char* __restrict__ Yf,
    const float* __restrict__ xx, const float* __restrict__ yy,
    unsigned* __restrict__ rowmin, unsigned* __restrict__ colmin)
{
  __shared__ __align__(16) unsigned char S[4][4096];   // 4-tile rotation
  __shared__ unsigned cmin_s[512];                     // col-min table

  const int bid = blockIdx.x;
  const int b   = bid & 7;                   // batch == XCD (L2 locality)
  const int rt  = (bid >> 3) & 31;           // 32 row-tiles of 128
  const int cq  = bid >> 8;                  // 0..7 col-eighths of 512
  const int n0  = rt * 128;
  const int m0  = cq * 512;

  const int t = threadIdx.x, lane = t & 63, wave = t >> 6;
  const int quad = lane >> 4, lcol = lane & 15;

  cmin_s[t]       = 0x7f800000u;
  cmin_s[t + 256] = 0x7f800000u;

  // ---- A fragments -> registers (coalesced dwordx4 from fragment blob) ----
  i32x8 af[2][2];
#pragma unroll
  for (int i = 0; i < 2; ++i) {
    const size_t g = (size_t)(b * 256 + rt * 8 + wave * 2 + i);
#pragma unroll
    for (int kt = 0; kt < 2; ++kt) {
      const uint4* p = (const uint4*)(Xf + ((g * 2 + kt) << 11));
      uint4* h = (uint4*)&af[i][kt];
      h[0] = p[lane];        // h=0
      h[1] = p[64 + lane];   // h=1
    }
  }

  float xv[2][4], rmin[2][4];
  const float* xxp = xx + b * N_ + n0 + wave * 32;
#pragma unroll
  for (int i = 0; i < 2; ++i)
#pragma unroll
    for (int r = 0; r < 4; ++r) {
      xv[i][r] = xxp[i * 16 + quad * 4 + r];
      rmin[i][r] = 1e30f;
    }

  // B staging: ct tile = one g16 = 4 KB contiguous fragment blob; the LDS
  // image is an identity copy (chunk cd = t>>6 at cd*1024, lane slot t&63).
  const unsigned char* Ybase = Yf + ((size_t)(b * 256 + cq * 32) << 12);
  const float* yyp = yy + b * N_ + m0;

#define STAGE_B(ct_, buf_)                                                    \
  gl_lds16(Ybase + (((size_t)(ct_)) << 12) + t * 16, (buf_) + t * 16);

  auto do_ct = [&](int ct, const unsigned char* curb) {
    float yv = yyp[ct * 16 + lcol];

    f32x4 acc[2] = {};
#pragma unroll
    for (int kt = 0; kt < 2; ++kt) {
      i32x8 bq;                       // one live B fragment (kt-outer)
      uint4* h = (uint4*)&bq;
      h[0] = *(const uint4*)(curb + kt * 2048 + lane * 16);
      h[1] = *(const uint4*)(curb + kt * 2048 + 1024 + lane * 16);
      __builtin_amdgcn_s_setprio(1);
#pragma unroll
      for (int i = 0; i < 2; ++i)
        acc[i] = __builtin_amdgcn_mfma_scale_f32_16x16x128_f8f6f4(
            af[i][kt], bq, acc[i],
            0, 0,        // cbsz = A fmt e4m3, blgp = B fmt e4m3
            0, 127,      // scale A: opsel 0, e8m0 127 = 1.0
            0, 127);     // scale B
      __builtin_amdgcn_s_setprio(0);
    }

    // epilogue: C/D row = i*16 + quad*4 + r, col = lcol
    float tc[8];
#pragma unroll
    for (int i = 0; i < 2; ++i)
#pragma unroll
      for (int r = 0; r < 4; ++r) {
        float a = acc[i][r];
        rmin[i][r] = fminf(rmin[i][r], __builtin_fmaf(-2.0f, a, yv));
        tc[i * 4 + r] = __builtin_fmaf(-2.0f, a, xv[i][r]);
      }
    // min3-fusable tree: 3x v_min3 + 1x v_min
    float m1 = fminf(fminf(tc[0], tc[1]), tc[2]);
    float m2 = fminf(fminf(tc[3], tc[4]), tc[5]);
    float cm = fminf(fminf(m1, m2), fminf(tc[6], tc[7]));
    // all 64 lanes: 16 addresses, quads merge 4-way inside the one
    // ds_min_u32 issue; fire-and-forget -- no cross-lane latency chain.
    atomicMin(&cmin_s[ct * 16 + lcol], __float_as_uint(cm + yv));
  };

  // prologue: stage group 0 (tiles 0,1) into bufs 0,1
  STAGE_B(0, S[0]);
  STAGE_B(1, S[1]);

  for (int g = 0; g < 16; ++g) {
    __syncthreads();   // drains group-g staging; group g-1 bufs now free
    const int cur = (g & 1) * 2;
    if (g + 1 < 16) {
      const int nxt = ((g + 1) & 1) * 2;
      STAGE_B(2 * g + 2, S[nxt]);       // in flight across this whole group
      STAGE_B(2 * g + 3, S[nxt + 1]);
    }
    do_ct(2 * g,     S[cur]);           // no barrier between these two:
    do_ct(2 * g + 1, S[cur + 1]);       // ct2 reads overlap ct1 epilogue
  }

  // rowmin: one global atomic set per block (32 rows/wave)
#pragma unroll
  for (int i = 0; i < 2; ++i)
#pragma unroll
    for (int r = 0; r < 4; ++r) {
      float v = xv[i][r] + rmin[i][r];
#pragma unroll
      for (int m = 1; m < 16; m <<= 1) v = fminf(v, __shfl_xor(v, m, 64));
      if (lcol == 0)
        atomicMin(rowmin + b * N_ + n0 + wave * 32 + i * 16 + quad * 4 + r,
                  __float_as_uint(v));
    }

  __syncthreads();
  // colmin: flush LDS table to global
#pragma unroll
  for (int i = 0; i < 2; ++i) {
    int idx = t + i * 256;
    atomicMin(colmin + b * N_ + m0 + idx, cmin_s[idx]);
  }
#undef STAGE_B
}

// 64 blocks x 256 threads: 16384 uint4 = 65536 mins; wave-reduce + atomicAdd.
__global__ __launch_bounds__(256) void reduce_kernel(
    const unsigned* __restrict__ mins,   // rowmin then colmin, contiguous
    float* __restrict__ out)
{
  int idx = blockIdx.x * 256 + threadIdx.x;
  uint4 u = ((const uint4*)mins)[idx];
  float s = __uint_as_float(u.x) + __uint_as_float(u.y)
          + __uint_as_float(u.z) + __uint_as_float(u.w);
#pragma unroll
  for (int m = 1; m < 64; m <<= 1) s += __shfl_xor(s, m, 64);
  if ((threadIdx.x & 63) == 0) atomicAdd(out, s);
}

extern "C" void kernel_launch(void* const* d_in, const int* in_sizes, int n_in,
                              void* d_out, int out_size, void* d_ws, size_t ws_size,
                              hipStream_t stream) {
  const float* gts   = (const float*)d_in[0];   // [8,4096,256] fp32
  const float* preds = (const float*)d_in[1];   // [8,4096,256] fp32

  char* ws = (char*)d_ws;
  const size_t XB_BYTES = (size_t)B_ * N_ * D_;         // 8 MiB each (fp8)
  unsigned char* Xf     = (unsigned char*)ws;
  unsigned char* Yf     = (unsigned char*)(ws + XB_BYTES);
  float*    xx     = (float*)(ws + 2 * XB_BYTES);
  float*    yy     = (float*)(ws + 2 * XB_BYTES + (size_t)B_ * N_ * 4);
  unsigned* rowmin = (unsigned*)(ws + 2 * XB_BYTES + (size_t)B_ * N_ * 8);
  unsigned* colmin = (unsigned*)(ws + 2 * XB_BYTES + (size_t)B_ * N_ * 12);

  // 4096 row-groups of 16 (X then Y), one wave each -> 1024 blocks
  prep_kernel<<<1024, 256, 0, stream>>>(gts, preds, Xf, Yf, xx, yy, rowmin, colmin,
                                        (float*)d_out);

  // 8 batches x 32 row-tiles(128) x 8 col-eighths(512) = 2048 blocks = 8/CU
  chamfer_gemm<<<2048, 256, 0, stream>>>(Xf, Yf, xx, yy, rowmin, colmin);

  reduce_kernel<<<64, 256, 0, stream>>>(rowmin, (float*)d_out);
}

// Round 3
// 153.823 us; speedup vs baseline: 2.4294x; 2.4294x over previous
//
#include <hip/hip_runtime.h>

typedef int   i32x8 __attribute__((ext_vector_type(8)));
typedef float f32x4 __attribute__((ext_vector_type(4)));

#define B_   8
#define N_   4096
#define D_   256

// fp8 fragment-major blob layout:
//   blob[g16][kt][h] = 1 KB chunk; lane l's 16 bytes at +l*16 hold
//   P[g16*16 + (l&15)][k = kt*128 + (l>>4)*32 + h*16 .. +16]  (e4m3)

__device__ __forceinline__ void gl_lds16(const void* g, void* l) {
  __builtin_amdgcn_global_load_lds(
      (const __attribute__((address_space(1))) unsigned int*)g,
      (__attribute__((address_space(3))) unsigned int*)l, 16, 0, 0);
}

// sum of squares of the 4 e4m3 bytes in w (selector must be a literal)
__device__ __forceinline__ float sq8(unsigned w) {
  float f0 = __builtin_amdgcn_cvt_f32_fp8(w, 0);
  float f1 = __builtin_amdgcn_cvt_f32_fp8(w, 1);
  float f2 = __builtin_amdgcn_cvt_f32_fp8(w, 2);
  float f3 = __builtin_amdgcn_cvt_f32_fp8(w, 3);
  return f0 * f0 + f1 * f1 + f2 * f2 + f3 * f3;
}

// One wave per 16-row group: fp32 -> fp8 e4m3 convert (coalesced 1 KB float4
// reads), in-wave LDS transpose to fragment-major, norms of DEQUANTIZED
// values accumulated during readback, min-init.
__global__ __launch_bounds__(256) void prep_kernel(
    const float* __restrict__ x, const float* __restrict__ y,
    unsigned char* __restrict__ Xf, unsigned char* __restrict__ Yf,
    float* __restrict__ xx, float* __restrict__ yy,
    unsigned* __restrict__ rowmin, unsigned* __restrict__ colmin,
    float* __restrict__ out)
{
  __shared__ unsigned char T[4][16 * 272];   // 16 rows x 256B fp8 (+16 pad)
  if (blockIdx.x == 0 && threadIdx.x == 0) out[0] = 0.f;

  const int wv = threadIdx.x >> 6, lane = threadIdx.x & 63;
  const int wid = (blockIdx.x << 2) + wv;          // 0..4095

  const float* src; unsigned char* dst; float* nrm; unsigned* mn; int g;
  if (wid < 2048) { g = wid;        src = x; dst = Xf; nrm = xx; mn = rowmin; }
  else            { g = wid - 2048; src = y; dst = Yf; nrm = yy; mn = colmin; }

  unsigned char* tw = T[wv];
  const float* rp = src + (size_t)g * 16 * D_;
#pragma unroll
  for (int r = 0; r < 16; ++r) {
    float4 v = *(const float4*)(rp + r * D_ + lane * 4);   // 1 KB contiguous
    unsigned u = __builtin_amdgcn_cvt_pk_fp8_f32(v.x, v.y, 0, 0);
    u = __builtin_amdgcn_cvt_pk_fp8_f32(v.z, v.w, u, 1);   // bytes = x,y,z,w
    *(unsigned*)(tw + r * 272 + lane * 4) = u;
  }
  // Each wave only reads its own T[wv] slice; all cross-lane traffic is
  // intra-wave, so a wave-local lgkmcnt drain replaces the 4-wave rendezvous.
  asm volatile("s_waitcnt lgkmcnt(0)" ::: "memory");
  __builtin_amdgcn_wave_barrier();

  // fragment-order readback: row = lane&15, k-base = (lane>>4)*32
  float s = 0.f;
  const int row = lane & 15, ko = (lane >> 4) * 32;
#pragma unroll
  for (int kt = 0; kt < 2; ++kt)
#pragma unroll
    for (int h = 0; h < 2; ++h) {
      uint4 c = *(const uint4*)(tw + row * 272 + kt * 128 + ko + h * 16);
      s += sq8(c.x) + sq8(c.y) + sq8(c.z) + sq8(c.w);
      *(uint4*)(dst + ((((size_t)g * 2 + kt) * 2 + h) << 10) + lane * 16) = c;
    }
  s += __shfl_xor(s, 16, 64);   // fold quads: row (lane&15)'s full norm
  s += __shfl_xor(s, 32, 64);
  if      (lane < 16) nrm[g * 16 + lane] = s;
  else if (lane < 32) mn[g * 16 + lane - 16] = 0x7f800000u;   // +inf
}

// MX-fp8 chamfer GEMM (mfma_scale_f32_16x16x128_f8f6f4, scales = 1.0).
// Round-13: round-12's occupancy structure (128x512 blocks, grid 2048,
// ct = 16 cols = one 4 KB identity-copy staging tile, LDS 18.4 KB) was
// correct, but __launch_bounds__(256,8) capped VGPRs at 64 < ~80 live state
// -> 1.1 GB scratch spill traffic (FETCH 620 MB), 273 us. Fix: (256,6) ->
// 84-VGPR cap, state fits, blocks/CU = min(LDS 8, VGPR 6, grid 8) = 6
// (vs round-11's 4). 24 waves/CU for the same per-wave code.
__global__ __launch_bounds__(256, 6) void chamfer_gemm(
    const unsigned char* __restrict__ Xf, const unsigned char* __restrict__ Yf,
    const float* __restrict__ xx, const float* __restrict__ yy,
    unsigned* __restrict__ rowmin, unsigned* __restrict__ colmin)
{
  __shared__ __align__(16) unsigned char S[4][4096];   // 4-tile rotation
  __shared__ unsigned cmin_s[512];                     // col-min table

  const int bid = blockIdx.x;
  const int b   = bid & 7;                   // batch == XCD (L2 locality)
  const int rt  = (bid >> 3) & 31;           // 32 row-tiles of 128
  const int cq  = bid >> 8;                  // 0..7 col-eighths of 512
  const int n0  = rt * 128;
  const int m0  = cq * 512;

  const int t = threadIdx.x, lane = t & 63, wave = t >> 6;
  const int quad = lane >> 4, lcol = lane & 15;

  cmin_s[t]       = 0x7f800000u;
  cmin_s[t + 256] = 0x7f800000u;

  // ---- A fragments -> registers (coalesced dwordx4 from fragment blob) ----
  i32x8 af[2][2];
#pragma unroll
  for (int i = 0; i < 2; ++i) {
    const size_t g = (size_t)(b * 256 + rt * 8 + wave * 2 + i);
#pragma unroll
    for (int kt = 0; kt < 2; ++kt) {
      const uint4* p = (const uint4*)(Xf + ((g * 2 + kt) << 11));
      uint4* h = (uint4*)&af[i][kt];
      h[0] = p[lane];        // h=0
      h[1] = p[64 + lane];   // h=1
    }
  }

  float xv[2][4], rmin[2][4];
  const float* xxp = xx + b * N_ + n0 + wave * 32;
#pragma unroll
  for (int i = 0; i < 2; ++i)
#pragma unroll
    for (int r = 0; r < 4; ++r) {
      xv[i][r] = xxp[i * 16 + quad * 4 + r];
      rmin[i][r] = 1e30f;
    }

  // B staging: ct tile = one g16 = 4 KB contiguous fragment blob; the LDS
  // image is an identity copy (chunk cd = t>>6 at cd*1024, lane slot t&63).
  const unsigned char* Ybase = Yf + ((size_t)(b * 256 + cq * 32) << 12);
  const float* yyp = yy + b * N_ + m0;

#define STAGE_B(ct_, buf_)                                                    \
  gl_lds16(Ybase + (((size_t)(ct_)) << 12) + t * 16, (buf_) + t * 16);

  auto do_ct = [&](int ct, const unsigned char* curb) {
    float yv = yyp[ct * 16 + lcol];

    f32x4 acc[2] = {};
#pragma unroll
    for (int kt = 0; kt < 2; ++kt) {
      i32x8 bq;                       // one live B fragment (kt-outer)
      uint4* h = (uint4*)&bq;
      h[0] = *(const uint4*)(curb + kt * 2048 + lane * 16);
      h[1] = *(const uint4*)(curb + kt * 2048 + 1024 + lane * 16);
      __builtin_amdgcn_s_setprio(1);
#pragma unroll
      for (int i = 0; i < 2; ++i)
        acc[i] = __builtin_amdgcn_mfma_scale_f32_16x16x128_f8f6f4(
            af[i][kt], bq, acc[i],
            0, 0,        // cbsz = A fmt e4m3, blgp = B fmt e4m3
            0, 127,      // scale A: opsel 0, e8m0 127 = 1.0
            0, 127);     // scale B
      __builtin_amdgcn_s_setprio(0);
    }

    // epilogue: C/D row = i*16 + quad*4 + r, col = lcol
    float tc[8];
#pragma unroll
    for (int i = 0; i < 2; ++i)
#pragma unroll
      for (int r = 0; r < 4; ++r) {
        float a = acc[i][r];
        rmin[i][r] = fminf(rmin[i][r], __builtin_fmaf(-2.0f, a, yv));
        tc[i * 4 + r] = __builtin_fmaf(-2.0f, a, xv[i][r]);
      }
    // min3-fusable tree: 3x v_min3 + 1x v_min
    float m1 = fminf(fminf(tc[0], tc[1]), tc[2]);
    float m2 = fminf(fminf(tc[3], tc[4]), tc[5]);
    float cm = fminf(fminf(m1, m2), fminf(tc[6], tc[7]));
    // all 64 lanes: 16 addresses, quads merge 4-way inside the one
    // ds_min_u32 issue; fire-and-forget -- no cross-lane latency chain.
    atomicMin(&cmin_s[ct * 16 + lcol], __float_as_uint(cm + yv));
  };

  // prologue: stage group 0 (tiles 0,1) into bufs 0,1
  STAGE_B(0, S[0]);
  STAGE_B(1, S[1]);

  for (int g = 0; g < 16; ++g) {
    __syncthreads();   // drains group-g staging; group g-1 bufs now free
    const int cur = (g & 1) * 2;
    if (g + 1 < 16) {
      const int nxt = ((g + 1) & 1) * 2;
      STAGE_B(2 * g + 2, S[nxt]);       // in flight across this whole group
      STAGE_B(2 * g + 3, S[nxt + 1]);
    }
    do_ct(2 * g,     S[cur]);           // no barrier between these two:
    do_ct(2 * g + 1, S[cur + 1]);       // ct2 reads overlap ct1 epilogue
  }

  // rowmin: one global atomic set per block (32 rows/wave)
#pragma unroll
  for (int i = 0; i < 2; ++i)
#pragma unroll
    for (int r = 0; r < 4; ++r) {
      float v = xv[i][r] + rmin[i][r];
#pragma unroll
      for (int m = 1; m < 16; m <<= 1) v = fminf(v, __shfl_xor(v, m, 64));
      if (lcol == 0)
        atomicMin(rowmin + b * N_ + n0 + wave * 32 + i * 16 + quad * 4 + r,
                  __float_as_uint(v));
    }

  __syncthreads();
  // colmin: flush LDS table to global
#pragma unroll
  for (int i = 0; i < 2; ++i) {
    int idx = t + i * 256;
    atomicMin(colmin + b * N_ + m0 + idx, cmin_s[idx]);
  }
#undef STAGE_B
}

// 64 blocks x 256 threads: 16384 uint4 = 65536 mins; wave-reduce + atomicAdd.
__global__ __launch_bounds__(256) void reduce_kernel(
    const unsigned* __restrict__ mins,   // rowmin then colmin, contiguous
    float* __restrict__ out)
{
  int idx = blockIdx.x * 256 + threadIdx.x;
  uint4 u = ((const uint4*)mins)[idx];
  float s = __uint_as_float(u.x) + __uint_as_float(u.y)
          + __uint_as_float(u.z) + __uint_as_float(u.w);
#pragma unroll
  for (int m = 1; m < 64; m <<= 1) s += __shfl_xor(s, m, 64);
  if ((threadIdx.x & 63) == 0) atomicAdd(out, s);
}

extern "C" void kernel_launch(void* const* d_in, const int* in_sizes, int n_in,
                              void* d_out, int out_size, void* d_ws, size_t ws_size,
                              hipStream_t stream) {
  const float* gts   = (const float*)d_in[0];   // [8,4096,256] fp32
  const float* preds = (const float*)d_in[1];   // [8,4096,256] fp32

  char* ws = (char*)d_ws;
  const size_t XB_BYTES = (size_t)B_ * N_ * D_;         // 8 MiB each (fp8)
  unsigned char* Xf     = (unsigned char*)ws;
  unsigned char* Yf     = (unsigned char*)(ws + XB_BYTES);
  float*    xx     = (float*)(ws + 2 * XB_BYTES);
  float*    yy     = (float*)(ws + 2 * XB_BYTES + (size_t)B_ * N_ * 4);
  unsigned* rowmin = (unsigned*)(ws + 2 * XB_BYTES + (size_t)B_ * N_ * 8);
  unsigned* colmin = (unsigned*)(ws + 2 * XB_BYTES + (size_t)B_ * N_ * 12);

  // 4096 row-groups of 16 (X then Y), one wave each -> 1024 blocks
  prep_kernel<<<1024, 256, 0, stream>>>(gts, preds, Xf, Yf, xx, yy, rowmin, colmin,
                                        (float*)d_out);

  // 8 batches x 32 row-tiles(128) x 8 col-eighths(512) = 2048 blocks, 6/CU
  chamfer_gemm<<<2048, 256, 0, stream>>>(Xf, Yf, xx, yy, rowmin, colmin);

  reduce_kernel<<<64, 256, 0, stream>>>(rowmin, (float*)d_out);
}

// Round 4
// 134.866 us; speedup vs baseline: 2.7708x; 1.1406x over previous
//
#include <hip/hip_runtime.h>

typedef int   i32x8 __attribute__((ext_vector_type(8)));
typedef float f32x4 __attribute__((ext_vector_type(4)));

#define B_   8
#define N_   4096
#define D_   256

// fp8 fragment-major blob layout:
//   blob[g16][kt][h] = 1 KB chunk; lane l's 16 bytes at +l*16 hold
//   P[g16*16 + (l&15)][k = kt*128 + (l>>4)*32 + h*16 .. +16]  (e4m3)

__device__ __forceinline__ void gl_lds16(const void* g, void* l) {
  __builtin_amdgcn_global_load_lds(
      (const __attribute__((address_space(1))) unsigned int*)g,
      (__attribute__((address_space(3))) unsigned int*)l, 16, 0, 0);
}

// sum of squares of the 4 e4m3 bytes in w (selector must be a literal)
__device__ __forceinline__ float sq8(unsigned w) {
  float f0 = __builtin_amdgcn_cvt_f32_fp8(w, 0);
  float f1 = __builtin_amdgcn_cvt_f32_fp8(w, 1);
  float f2 = __builtin_amdgcn_cvt_f32_fp8(w, 2);
  float f3 = __builtin_amdgcn_cvt_f32_fp8(w, 3);
  return f0 * f0 + f1 * f1 + f2 * f2 + f3 * f3;
}

// One wave per 16-row group: fp32 -> fp8 e4m3 convert (coalesced 1 KB float4
// reads), in-wave LDS transpose to fragment-major, norms of DEQUANTIZED
// values accumulated during readback, min-init.
__global__ __launch_bounds__(256) void prep_kernel(
    const float* __restrict__ x, const float* __restrict__ y,
    unsigned char* __restrict__ Xf, unsigned char* __restrict__ Yf,
    float* __restrict__ xx, float* __restrict__ yy,
    unsigned* __restrict__ rowmin, unsigned* __restrict__ colmin,
    float* __restrict__ out)
{
  __shared__ unsigned char T[4][16 * 272];   // 16 rows x 256B fp8 (+16 pad)
  if (blockIdx.x == 0 && threadIdx.x == 0) out[0] = 0.f;

  const int wv = threadIdx.x >> 6, lane = threadIdx.x & 63;
  const int wid = (blockIdx.x << 2) + wv;          // 0..4095

  const float* src; unsigned char* dst; float* nrm; unsigned* mn; int g;
  if (wid < 2048) { g = wid;        src = x; dst = Xf; nrm = xx; mn = rowmin; }
  else            { g = wid - 2048; src = y; dst = Yf; nrm = yy; mn = colmin; }

  unsigned char* tw = T[wv];
  const float* rp = src + (size_t)g * 16 * D_;
#pragma unroll
  for (int r = 0; r < 16; ++r) {
    float4 v = *(const float4*)(rp + r * D_ + lane * 4);   // 1 KB contiguous
    unsigned u = __builtin_amdgcn_cvt_pk_fp8_f32(v.x, v.y, 0, 0);
    u = __builtin_amdgcn_cvt_pk_fp8_f32(v.z, v.w, u, 1);   // bytes = x,y,z,w
    *(unsigned*)(tw + r * 272 + lane * 4) = u;
  }
  // Each wave only reads its own T[wv] slice; all cross-lane traffic is
  // intra-wave, so a wave-local lgkmcnt drain replaces the 4-wave rendezvous.
  asm volatile("s_waitcnt lgkmcnt(0)" ::: "memory");
  __builtin_amdgcn_wave_barrier();

  // fragment-order readback: row = lane&15, k-base = (lane>>4)*32
  float s = 0.f;
  const int row = lane & 15, ko = (lane >> 4) * 32;
#pragma unroll
  for (int kt = 0; kt < 2; ++kt)
#pragma unroll
    for (int h = 0; h < 2; ++h) {
      uint4 c = *(const uint4*)(tw + row * 272 + kt * 128 + ko + h * 16);
      s += sq8(c.x) + sq8(c.y) + sq8(c.z) + sq8(c.w);
      *(uint4*)(dst + ((((size_t)g * 2 + kt) * 2 + h) << 10) + lane * 16) = c;
    }
  s += __shfl_xor(s, 16, 64);   // fold quads: row (lane&15)'s full norm
  s += __shfl_xor(s, 32, 64);
  if      (lane < 16) nrm[g * 16 + lane] = s;
  else if (lane < 32) mn[g * 16 + lane - 16] = 0x7f800000u;   // +inf
}

// MX-fp8 chamfer GEMM (mfma_scale_f32_16x16x128_f8f6f4, scales = 1.0).
// Round-14: register-tile doubling (i=4). Pipe arithmetic for the old
// 32-rows/wave shape: LDS pipe = 1 ds_read_b128 per MFMA = 20.5 us/CU --
// the TALLEST floor (mfma 14.7, VALU ~11); occupancy pushes (r12/r13) made
// things worse. Each wave now owns 64 rows (af[4][2], 64 VGPR), so
// MFMA:ds_read = 2:1 -> LDS pipe ~10 us, below the MFMA floor. Blocks:
// 256 rows x 512 cols, grid = 8b x 16rt x 8cq = 1024 (single full round).
// ~210 VGPR -> 2 waves/SIMD; the bet is per-wave ILP (16 mfma vs ~400 cyc
// issue per ct) feeds the matrix pipe at 2 waves/SIMD. launch_bounds(256,2)
// = cap 256: spill-impossible (r12 lesson). Barriers also drop to 8/block.
__global__ __launch_bounds__(256, 2) void chamfer_gemm(
    const unsigned char* __restrict__ Xf, const unsigned char* __restrict__ Yf,
    const float* __restrict__ xx, const float* __restrict__ yy,
    unsigned* __restrict__ rowmin, unsigned* __restrict__ colmin)
{
  __shared__ __align__(16) unsigned char S[4][8192];   // 4-tile rotation
  __shared__ unsigned cmin_s[512];                     // col-min table

  const int bid = blockIdx.x;
  const int b   = bid & 7;                   // batch == XCD (L2 locality)
  const int rt  = (bid >> 3) & 15;           // 16 row-tiles of 256
  const int cq  = bid >> 7;                  // 0..7 col-eighths of 512
  const int n0  = rt * 256;
  const int m0  = cq * 512;

  const int t = threadIdx.x, lane = t & 63, wave = t >> 6;
  const int quad = lane >> 4, lcol = lane & 15;

  cmin_s[t]       = 0x7f800000u;
  cmin_s[t + 256] = 0x7f800000u;

  // ---- A fragments -> registers (coalesced dwordx4 from fragment blob) ----
  // wave owns 64 rows: g16 = b*256 + rt*16 + wave*4 + i, i = 0..3
  i32x8 af[4][2];
#pragma unroll
  for (int i = 0; i < 4; ++i) {
    const size_t g = (size_t)(b * 256 + rt * 16 + wave * 4 + i);
#pragma unroll
    for (int kt = 0; kt < 2; ++kt) {
      const uint4* p = (const uint4*)(Xf + ((g * 2 + kt) << 11));
      uint4* h = (uint4*)&af[i][kt];
      h[0] = p[lane];        // h=0
      h[1] = p[64 + lane];   // h=1
    }
  }

  float xv[4][4], rmin[4][4];
  const float* xxp = xx + b * N_ + n0 + wave * 64;
#pragma unroll
  for (int i = 0; i < 4; ++i)
#pragma unroll
    for (int r = 0; r < 4; ++r) {
      xv[i][r] = xxp[i * 16 + quad * 4 + r];
      rmin[i][r] = 1e30f;
    }

  // B staging: LDS chunk cd = kt*4 + h*2 + j at cd*1024; slot s = t + h2*256
  // -> cd = s>>6 (wave-uniform), lane slot = s&63. Source chunk is a
  // contiguous 1 KB of the fragment blob -> perfectly coalesced.
  const unsigned char* Ybase = Yf + ((size_t)(b * 256 + cq * 32) << 12);
  const float* yyp = yy + b * N_ + m0;

#define STAGE_B(ct_, buf_)                                                    \
  {                                                                           \
    const unsigned char* Ysrc = Ybase + ((size_t)(ct_) << 13);  /* 2 g16 */   \
    _Pragma("unroll")                                                         \
    for (int h2 = 0; h2 < 2; ++h2) {                                          \
      int s  = t + h2 * 256;                                                  \
      int cd = s >> 6, ln = s & 63;                                           \
      int kt = cd >> 2, hh = (cd >> 1) & 1, jj = cd & 1;                      \
      gl_lds16(Ysrc + jj * 4096 + kt * 2048 + hh * 1024 + ln * 16,            \
               (buf_) + s * 16);                                              \
    }                                                                         \
  }

  auto do_ct = [&](int ct, const unsigned char* curb) {
    float yv0 = yyp[ct * 32 + lcol];
    float yv1 = yyp[ct * 32 + 16 + lcol];

    // B fragments: bq[j][kt] from chunks (kt, h, j) -- ds_read_b128 straight
    // into the operand halves (no repack movs)
    i32x8 bq[2][2];
#pragma unroll
    for (int j = 0; j < 2; ++j)
#pragma unroll
      for (int kt = 0; kt < 2; ++kt) {
        uint4* h = (uint4*)&bq[j][kt];
        h[0] = *(const uint4*)(curb + (kt * 4 + 0 + j) * 1024 + lane * 16);
        h[1] = *(const uint4*)(curb + (kt * 4 + 2 + j) * 1024 + lane * 16);
      }

    f32x4 acc[4][2] = {};
    __builtin_amdgcn_s_setprio(1);
#pragma unroll
    for (int kt = 0; kt < 2; ++kt)
#pragma unroll
      for (int i = 0; i < 4; ++i)
#pragma unroll
        for (int j = 0; j < 2; ++j)
          acc[i][j] = __builtin_amdgcn_mfma_scale_f32_16x16x128_f8f6f4(
              af[i][kt], bq[j][kt], acc[i][j],
              0, 0,        // cbsz = A fmt e4m3, blgp = B fmt e4m3
              0, 127,      // scale A: opsel 0, e8m0 127 = 1.0
              0, 127);     // scale B
    __builtin_amdgcn_s_setprio(0);

    // epilogue: C/D row = i*16 + quad*4 + r, col = j*16 + lcol
#pragma unroll
    for (int j = 0; j < 2; ++j) {
      float yv = j ? yv1 : yv0;
      float tc[16];
#pragma unroll
      for (int i = 0; i < 4; ++i)
#pragma unroll
        for (int r = 0; r < 4; ++r) {
          float a = acc[i][j][r];
          rmin[i][r] = fminf(rmin[i][r], __builtin_fmaf(-2.0f, a, yv));
          tc[i * 4 + r] = __builtin_fmaf(-2.0f, a, xv[i][r]);
        }
      // balanced min tree of 16 (compiler fuses to v_min3 chains)
      float m0_ = fminf(fminf(tc[0], tc[1]), fminf(tc[2], tc[3]));
      float m1_ = fminf(fminf(tc[4], tc[5]), fminf(tc[6], tc[7]));
      float m2_ = fminf(fminf(tc[8], tc[9]), fminf(tc[10], tc[11]));
      float m3_ = fminf(fminf(tc[12], tc[13]), fminf(tc[14], tc[15]));
      float cm  = fminf(fminf(m0_, m1_), fminf(m2_, m3_));
      // all 64 lanes: 16 addresses, quads merge 4-way inside the one
      // ds_min_u32 issue; fire-and-forget -- no cross-lane latency chain.
      atomicMin(&cmin_s[ct * 32 + j * 16 + lcol], __float_as_uint(cm + yv));
    }
  };

  // prologue: stage group 0 (tiles 0,1) into bufs 0,1
  STAGE_B(0, S[0]);
  STAGE_B(1, S[1]);

  for (int g = 0; g < 8; ++g) {
    __syncthreads();   // drains group-g staging; group g-1 bufs now free
    const int cur = (g & 1) * 2;
    if (g + 1 < 8) {
      const int nxt = ((g + 1) & 1) * 2;
      STAGE_B(2 * g + 2, S[nxt]);       // in flight across this whole group
      STAGE_B(2 * g + 3, S[nxt + 1]);
    }
    do_ct(2 * g,     S[cur]);           // no barrier between these two:
    do_ct(2 * g + 1, S[cur + 1]);       // ct2 reads overlap ct1 epilogue
  }

  // rowmin: one global atomic set per block (64 rows/wave)
#pragma unroll
  for (int i = 0; i < 4; ++i)
#pragma unroll
    for (int r = 0; r < 4; ++r) {
      float v = xv[i][r] + rmin[i][r];
#pragma unroll
      for (int m = 1; m < 16; m <<= 1) v = fminf(v, __shfl_xor(v, m, 64));
      if (lcol == 0)
        atomicMin(rowmin + b * N_ + n0 + wave * 64 + i * 16 + quad * 4 + r,
                  __float_as_uint(v));
    }

  __syncthreads();
  // colmin: flush LDS table to global
#pragma unroll
  for (int i = 0; i < 2; ++i) {
    int idx = t + i * 256;
    atomicMin(colmin + b * N_ + m0 + idx, cmin_s[idx]);
  }
#undef STAGE_B
}

// 64 blocks x 256 threads: 16384 uint4 = 65536 mins; wave-reduce + atomicAdd.
__global__ __launch_bounds__(256) void reduce_kernel(
    const unsigned* __restrict__ mins,   // rowmin then colmin, contiguous
    float* __restrict__ out)
{
  int idx = blockIdx.x * 256 + threadIdx.x;
  uint4 u = ((const uint4*)mins)[idx];
  float s = __uint_as_float(u.x) + __uint_as_float(u.y)
          + __uint_as_float(u.z) + __uint_as_float(u.w);
#pragma unroll
  for (int m = 1; m < 64; m <<= 1) s += __shfl_xor(s, m, 64);
  if ((threadIdx.x & 63) == 0) atomicAdd(out, s);
}

extern "C" void kernel_launch(void* const* d_in, const int* in_sizes, int n_in,
                              void* d_out, int out_size, void* d_ws, size_t ws_size,
                              hipStream_t stream) {
  const float* gts   = (const float*)d_in[0];   // [8,4096,256] fp32
  const float* preds = (const float*)d_in[1];   // [8,4096,256] fp32

  char* ws = (char*)d_ws;
  const size_t XB_BYTES = (size_t)B_ * N_ * D_;         // 8 MiB each (fp8)
  unsigned char* Xf     = (unsigned char*)ws;
  unsigned char* Yf     = (unsigned char*)(ws + XB_BYTES);
  float*    xx     = (float*)(ws + 2 * XB_BYTES);
  float*    yy     = (float*)(ws + 2 * XB_BYTES + (size_t)B_ * N_ * 4);
  unsigned* rowmin = (unsigned*)(ws + 2 * XB_BYTES + (size_t)B_ * N_ * 8);
  unsigned* colmin = (unsigned*)(ws + 2 * XB_BYTES + (size_t)B_ * N_ * 12);

  // 4096 row-groups of 16 (X then Y), one wave each -> 1024 blocks
  prep_kernel<<<1024, 256, 0, stream>>>(gts, preds, Xf, Yf, xx, yy, rowmin, colmin,
                                        (float*)d_out);

  // 8 batches x 16 row-tiles(256) x 8 col-eighths(512) = 1024 blocks
  chamfer_gemm<<<1024, 256, 0, stream>>>(Xf, Yf, xx, yy, rowmin, colmin);

  reduce_kernel<<<64, 256, 0, stream>>>(rowmin, (float*)d_out);
}